// Round 1
// baseline (41736.176 us; speedup 1.0000x reference)
//
#include <hip/hip_runtime.h>
#include <cstddef>

#define BB 32
#define TT 512
#define HH 512

// ---------------------------------------------------------------------------
// ws layout (floats):
//   h0   @ 0        : [32][512]
//   h1   @ 16384    : [32][512]
//   y0   @ 32768    : [2][32][512]   (layer-0 output double buffer, t&1)
//   rh   @ 65536    : [2][32][512]   (r * h, per layer)
//   uu   @ 98304    : [2][32][512]   (update gate u, per layer)
//   WgT  @ 131072   : [2][1024][1024]  (transposed gate weights: [l][col][i])
//   WcT  @ 2228224  : [2][512][1024]   (transposed cand weights: [l][col][i])
// total = 3276800 floats = 13107200 bytes
// ---------------------------------------------------------------------------

template <int R, int C>
__global__ __launch_bounds__(256) void transpose_k(const float* __restrict__ src,
                                                   float* __restrict__ dst) {
    __shared__ float tile[32][33];
    const int tx = threadIdx.x & 31;
    const int ty = threadIdx.x >> 5;  // 0..7
    const int tiles_c = C / 32;
    const int bc_ = blockIdx.x % tiles_c;
    const int br_ = blockIdx.x / tiles_c;
    const int r0 = br_ * 32, c0 = bc_ * 32;
#pragma unroll
    for (int k = 0; k < 32; k += 8)
        tile[ty + k][tx] = src[(size_t)(r0 + ty + k) * C + (c0 + tx)];
    __syncthreads();
#pragma unroll
    for (int k = 0; k < 32; k += 8)
        dst[(size_t)(c0 + ty + k) * R + (r0 + tx)] = tile[tx][ty + k];
}

// Gates phase: for layer l (l=0 at step t, l=1 at step t-1):
//   g[b,j] = sigmoid( [in_t, h] . Wg[:,j] + bg[j] ),  j in [0,1024)
//   r = g[:, :512] -> store rh = r*h ;  u = g[:, 512:] -> store uu
// Block: 256 thr = 32 batches x 8 cols. Blocks 0..127 layer0, 128..255 layer1.
__global__ __launch_bounds__(256) void gates_k(
    const float* __restrict__ x, const float* __restrict__ y0,
    const float* __restrict__ h0, const float* __restrict__ h1,
    const float* __restrict__ WgT, const float* __restrict__ bg,
    float* __restrict__ rh, float* __restrict__ uu, int t) {
    const int l = blockIdx.x >> 7;  // 0 or 1
    const int tt = t - l;           // layer0 processes t, layer1 processes t-1
    if (tt < 0 || tt >= TT) return;
    const int chunk = blockIdx.x & 127;
    const int j = chunk * 8 + (threadIdx.x & 7);  // 0..1023
    const int b = threadIdx.x >> 3;               // 0..31

    const float* __restrict__ in =
        (l == 0) ? (x + ((size_t)b * TT + tt) * HH)
                 : (y0 + ((size_t)(tt & 1) * BB + b) * HH);
    const float* __restrict__ hp = ((l == 0) ? h0 : h1) + (size_t)b * HH;
    const float* __restrict__ w = WgT + ((size_t)l * 1024 + j) * 1024;

    float acc = bg[l * 1024 + j];
#pragma unroll 8
    for (int i = 0; i < HH; i += 4) {
        const float4 wv = *(const float4*)(w + i);
        const float4 iv = *(const float4*)(in + i);
        acc += wv.x * iv.x + wv.y * iv.y + wv.z * iv.z + wv.w * iv.w;
    }
#pragma unroll 8
    for (int i = 0; i < HH; i += 4) {
        const float4 wv = *(const float4*)(w + HH + i);
        const float4 hv = *(const float4*)(hp + i);
        acc += wv.x * hv.x + wv.y * hv.y + wv.z * hv.z + wv.w * hv.w;
    }
    const float g = 1.0f / (1.0f + expf(-acc));
    if (j < HH)
        rh[((size_t)l * BB + b) * HH + j] = g * hp[j];
    else
        uu[((size_t)l * BB + b) * HH + (j - HH)] = g;
}

// Candidate + state update phase:
//   c[b,m] = tanh( [in_t, r*h] . Wc[:,m] + bc[m] )
//   h_new  = u*h + (1-u)*c ;  masked by t < seq_len
// Block: 256 thr = 32 batches x 8 cols. Blocks 0..63 layer0, 64..127 layer1.
__global__ __launch_bounds__(256) void cand_k(
    const float* __restrict__ x, float* __restrict__ y0,
    float* __restrict__ h0, float* __restrict__ h1,
    const float* __restrict__ WcT, const float* __restrict__ bc,
    const float* __restrict__ rh, const float* __restrict__ uu,
    const int* __restrict__ seq_lens, float* __restrict__ out, int t) {
    const int l = blockIdx.x >> 6;
    const int tt = t - l;
    if (tt < 0 || tt >= TT) return;
    const int chunk = blockIdx.x & 63;
    const int m = chunk * 8 + (threadIdx.x & 7);  // 0..511
    const int b = threadIdx.x >> 3;               // 0..31

    const float* __restrict__ in =
        (l == 0) ? (x + ((size_t)b * TT + tt) * HH)
                 : (y0 + ((size_t)(tt & 1) * BB + b) * HH);
    const float* __restrict__ rhp = rh + ((size_t)l * BB + b) * HH;
    const float* __restrict__ w = WcT + ((size_t)l * 512 + m) * 1024;

    float acc = bc[l * 512 + m];
#pragma unroll 8
    for (int i = 0; i < HH; i += 4) {
        const float4 wv = *(const float4*)(w + i);
        const float4 iv = *(const float4*)(in + i);
        acc += wv.x * iv.x + wv.y * iv.y + wv.z * iv.z + wv.w * iv.w;
    }
#pragma unroll 8
    for (int i = 0; i < HH; i += 4) {
        const float4 wv = *(const float4*)(w + HH + i);
        const float4 rv = *(const float4*)(rhp + i);
        acc += wv.x * rv.x + wv.y * rv.y + wv.z * rv.z + wv.w * rv.w;
    }
    const float c = tanhf(acc);

    float* __restrict__ hptr = (l == 0) ? h0 : h1;
    const float hold = hptr[(size_t)b * HH + m];
    const float u = uu[((size_t)l * BB + b) * HH + m];
    const float hn = u * hold + (1.0f - u) * c;
    const bool act = tt < seq_lens[b];
    const float hnew = act ? hn : hold;
    const float y = act ? hn : 0.0f;

    hptr[(size_t)b * HH + m] = hnew;
    if (l == 0)
        y0[((size_t)(tt & 1) * BB + b) * HH + m] = y;
    else
        out[((size_t)b * TT + tt) * HH + m] = y;
}

extern "C" void kernel_launch(void* const* d_in, const int* in_sizes, int n_in,
                              void* d_out, int out_size, void* d_ws, size_t ws_size,
                              hipStream_t stream) {
    const float* x = (const float*)d_in[0];
    const int* seq_lens = (const int*)d_in[1];
    const float* Wg = (const float*)d_in[2];
    const float* bg = (const float*)d_in[3];
    const float* Wc = (const float*)d_in[4];
    const float* bc = (const float*)d_in[5];
    float* out = (float*)d_out;
    float* ws = (float*)d_ws;

    float* h0 = ws;
    float* h1 = ws + 16384;
    float* y0 = ws + 32768;
    float* rhb = ws + 65536;
    float* uub = ws + 98304;
    float* WgT = ws + 131072;
    float* WcT = ws + 2228224;

    // zero initial hidden states (deterministic every launch)
    hipMemsetAsync(ws, 0, 2 * BB * HH * sizeof(float), stream);

    // transpose weights so dot loops can use float4 loads on both operands
    transpose_k<1024, 1024><<<1024, 256, 0, stream>>>(Wg, WgT);
    transpose_k<1024, 1024><<<1024, 256, 0, stream>>>(Wg + 1024 * 1024, WgT + 1024 * 1024);
    transpose_k<1024, 512><<<512, 256, 0, stream>>>(Wc, WcT);
    transpose_k<1024, 512><<<512, 256, 0, stream>>>(Wc + 1024 * 512, WcT + 512 * 1024);

    // software-pipelined recurrence: layer 1 lags layer 0 by one step.
    // phaseA(t): gates for L0@t and L1@(t-1); phaseB(t): cand+update for both.
    for (int t = 0; t <= TT; ++t) {
        gates_k<<<256, 256, 0, stream>>>(x, y0, h0, h1, WgT, bg, rhb, uub, t);
        cand_k<<<128, 256, 0, stream>>>(x, y0, h0, h1, WcT, bc, rhb, uub, seq_lens, out, t);
    }
}